// Round 6
// baseline (253.286 us; speedup 1.0000x reference)
//
#include <hip/hip_runtime.h>
#include <hip/hip_bf16.h>
#include <math.h>

#define BB 32
#define SS 4096
#define HH 256

typedef __bf16 bf16x8 __attribute__((ext_vector_type(8)));
typedef float f32x4 __attribute__((ext_vector_type(4)));

__device__ inline bf16x8 cvt8(const float4& x, const float4& y) {
    union { __hip_bfloat162 p[4]; bf16x8 v; } u;
    u.p[0] = __float22bfloat162_rn(make_float2(x.x, x.y));
    u.p[1] = __float22bfloat162_rn(make_float2(x.z, x.w));
    u.p[2] = __float22bfloat162_rn(make_float2(y.x, y.y));
    u.p[3] = __float22bfloat162_rn(make_float2(y.z, y.w));
    return u.v;
}

// tanh via exp path: ~6 VALU ops. |rel err| ~1e-7.
__device__ inline float fast_tanh(float x) {
    float xc = fminf(fmaxf(x, -10.f), 10.f);
    float e  = __expf(2.f * xc);
    return (e - 1.f) * __builtin_amdgcn_rcpf(e + 1.f);
}

// ---------------------------------------------------------------------------
// Prep (fused): blocks 0..255 swizzle W2 -> bf16 MFMA-B order;
// blocks 256..287: qq[b][h] = hidden[b]@W1[:,h] + W1_b[h] + W2_b[h];
// block 288: M = sum_h |V_w[h]| (fixed softmax shift; V_b cancels).
// w2sw[((kc*16+nt)*64+lane)*8+j] = W2[kc*32+(lane>>4)*8+j][nt*16+(lane&15)]
// ---------------------------------------------------------------------------
__global__ void prep_kernel(const float* __restrict__ W2_w,
                            ushort* __restrict__ w2sw,
                            const float* __restrict__ hidden,
                            const float* __restrict__ W1_w,
                            const float* __restrict__ W1_b,
                            const float* __restrict__ W2_b,
                            const float* __restrict__ V_w,
                            float* __restrict__ qq,
                            float* __restrict__ Mout) {
    __shared__ float red[HH];
    const int t = threadIdx.x;
    if (blockIdx.x < 256) {
        const int i = blockIdx.x * 256 + t;
        const int j    = i & 7;
        const int lane = (i >> 3) & 63;
        const int nt   = (i >> 9) & 15;
        const int kc   = i >> 13;
        const int k = kc * 32 + ((lane >> 4) & 3) * 8 + j;
        const int n = nt * 16 + (lane & 15);
        __hip_bfloat16 h = __float2bfloat16(W2_w[k * HH + n]);
        w2sw[i] = *(ushort*)&h;
    } else if (blockIdx.x < 256 + BB) {
        const int b = blockIdx.x - 256;
        red[t] = hidden[b * HH + t];
        __syncthreads();
        float acc = 0.f;
#pragma unroll 16
        for (int k = 0; k < HH; ++k)
            acc = fmaf(red[k], W1_w[k * HH + t], acc);
        qq[b * HH + t] = acc + W1_b[t] + W2_b[t];
    } else {
        red[t] = fabsf(V_w[t]);
        __syncthreads();
        for (int off = 128; off > 0; off >>= 1) {
            if (t < off) red[t] += red[t + off];
            __syncthreads();
        }
        if (t == 0) Mout[0] = red[0];
    }
}

// ---------------------------------------------------------------------------
// Fused score + partial-context kernel: grid (SS/64, BB), block 256
// = 4 waves as 2(m) x 2(n); tile 64 s-rows x 256 n.
// B-fragments loaded DIRECTLY global->registers (W2 is L2-resident after
// first touch; loads are 1KB/wave coalesced dwordx4). No LDS staging and
// therefore NO __syncthreads in the K-loop -> loads stay in flight
// continuously (the R5 barrier drained vmcnt(0) every iteration).
// 1-deep software pipeline on both A (enc, HBM) and B (W2, L2).
// Epilogue: wtilde = exp(V.tanh(qq+k) - M) -> d_out weights slot;
// local ctx partial over own 64 enc rows (cache-hot).
// ---------------------------------------------------------------------------
__global__ __launch_bounds__(256, 2)
void score_ctx_kernel(const float* __restrict__ enc,
                      const ushort* __restrict__ w2sw,
                      const float* __restrict__ qq,
                      const float* __restrict__ V_w,
                      const float* __restrict__ Mptr,
                      float* __restrict__ wtilde_out,
                      float* __restrict__ part) {
    __shared__ float sc_lds[64];
    __shared__ float accl[4][HH];

    const int t    = threadIdx.x;
    const int b    = blockIdx.y;
    const int c    = blockIdx.x;
    const int s0   = c * 64;
    const int wave = t >> 6;
    const int lane = t & 63;
    const int mw   = wave & 1;
    const int nw   = wave >> 1;
    const int l15  = lane & 15;
    const int quad = lane >> 4;

    f32x4 acc[2][8];
#pragma unroll
    for (int mt = 0; mt < 2; ++mt)
#pragma unroll
        for (int nt = 0; nt < 8; ++nt) acc[mt][nt] = (f32x4)0.f;

    // B: global bf16x8 index kc*1024 + (nw*8+nt)*64 + lane
    const bf16x8* bgl = (const bf16x8*)w2sw + (size_t)(nw * 8) * 64 + lane;
    // A: rows s0 + mw*32 + mt*16 + l15, k = kc*32 + quad*8 + j
    const float* aptr0 =
        enc + ((size_t)(b * SS + s0 + mw * 32 + l15)) * HH + quad * 8;
    const float* aptr1 = aptr0 + (size_t)16 * HH;

    bf16x8 bq[2][8];
    float4 ax[2][2], ay[2][2];   // [parity][mt]

#pragma unroll
    for (int nt = 0; nt < 8; ++nt) bq[0][nt] = bgl[nt * 64];
    ax[0][0] = *(const float4*)aptr0;
    ay[0][0] = *(const float4*)(aptr0 + 4);
    ax[0][1] = *(const float4*)aptr1;
    ay[0][1] = *(const float4*)(aptr1 + 4);

#pragma unroll
    for (int kc = 0; kc < 8; ++kc) {
        const int cur = kc & 1;
        if (kc < 7) {
#pragma unroll
            for (int nt = 0; nt < 8; ++nt)
                bq[cur ^ 1][nt] = bgl[(kc + 1) * 1024 + nt * 64];
            const int o = (kc + 1) * 32;
            ax[cur ^ 1][0] = *(const float4*)(aptr0 + o);
            ay[cur ^ 1][0] = *(const float4*)(aptr0 + o + 4);
            ax[cur ^ 1][1] = *(const float4*)(aptr1 + o);
            ay[cur ^ 1][1] = *(const float4*)(aptr1 + o + 4);
        }
        bf16x8 af0 = cvt8(ax[cur][0], ay[cur][0]);
        bf16x8 af1 = cvt8(ax[cur][1], ay[cur][1]);
#pragma unroll
        for (int nt = 0; nt < 8; ++nt) {
            acc[0][nt] = __builtin_amdgcn_mfma_f32_16x16x32_bf16(
                af0, bq[cur][nt], acc[0][nt], 0, 0, 0);
            acc[1][nt] = __builtin_amdgcn_mfma_f32_16x16x32_bf16(
                af1, bq[cur][nt], acc[1][nt], 0, 0, 0);
        }
    }

    // Epilogue: C layout col = l15, local row = quad*4 + r.
    float p[2][4] = {{0.f, 0.f, 0.f, 0.f}, {0.f, 0.f, 0.f, 0.f}};
#pragma unroll
    for (int nt = 0; nt < 8; ++nt) {
        const int n = nw * 128 + nt * 16 + l15;
        const float qn = qq[b * HH + n];
        const float vn = V_w[n];
#pragma unroll
        for (int mt = 0; mt < 2; ++mt)
#pragma unroll
            for (int r = 0; r < 4; ++r)
                p[mt][r] = fmaf(vn, fast_tanh(qn + acc[mt][nt][r]), p[mt][r]);
    }
#pragma unroll
    for (int off = 1; off < 16; off <<= 1)
#pragma unroll
        for (int mt = 0; mt < 2; ++mt)
#pragma unroll
            for (int r = 0; r < 4; ++r)
                p[mt][r] += __shfl_xor(p[mt][r], off);

    if (nw == 0 && l15 == 0) {
#pragma unroll
        for (int mt = 0; mt < 2; ++mt)
            *(float4*)&sc_lds[mw * 32 + mt * 16 + quad * 4] =
                make_float4(p[mt][0], p[mt][1], p[mt][2], p[mt][3]);
    }
    __syncthreads();
    const float Mv = Mptr[0];
    if (nw == 1 && l15 == 0) {
#pragma unroll
        for (int mt = 0; mt < 2; ++mt) {
            const int row = mw * 32 + mt * 16 + quad * 4;
            float4 h = *(const float4*)&sc_lds[row];
            float4 v = make_float4(__expf(h.x + p[mt][0] - Mv),
                                   __expf(h.y + p[mt][1] - Mv),
                                   __expf(h.z + p[mt][2] - Mv),
                                   __expf(h.w + p[mt][3] - Mv));
            *(float4*)&sc_lds[row] = v;
            *(float4*)&wtilde_out[b * SS + s0 + row] = v;
        }
    }
    __syncthreads();

    // Local context partial over this block's 64 rows (cache-hot).
    const int tr = t >> 6;
    const int h0 = (t & 63) * 4;
    float4 a = make_float4(0.f, 0.f, 0.f, 0.f);
    const float* ep = enc + ((size_t)(b * SS + s0)) * HH;
#pragma unroll
    for (int jj = 0; jj < 16; ++jj) {
        const int j = jj * 4 + tr;
        const float4 e = *(const float4*)(ep + (size_t)j * HH + h0);
        const float w = sc_lds[j];
        a.x = fmaf(w, e.x, a.x);
        a.y = fmaf(w, e.y, a.y);
        a.z = fmaf(w, e.z, a.z);
        a.w = fmaf(w, e.w, a.w);
    }
    *(float4*)&accl[tr][h0] = a;
    __syncthreads();

    part[((size_t)(b * 64 + c)) * HH + t] =
        accl[0][t] + accl[1][t] + accl[2][t] + accl[3][t];
}

// ---------------------------------------------------------------------------
// Finish: grid (BB), block 256. l = sum_s wtilde (read from d_out),
// weights normalized in place; ctx = (sum_c part)/l.
// ---------------------------------------------------------------------------
__global__ __launch_bounds__(256)
void finish_kernel(const float* __restrict__ part,
                   float* __restrict__ weights_out,
                   float* __restrict__ ctx_out) {
    __shared__ float red[256];
    __shared__ float linv_s;
    const int b = blockIdx.x;
    const int t = threadIdx.x;

    float4* wo4 = (float4*)(weights_out + (size_t)b * SS);
    float4 vals[4];
    float l = 0.f;
#pragma unroll
    for (int i = 0; i < 4; ++i) {
        vals[i] = wo4[i * 256 + t];
        l += vals[i].x + vals[i].y + vals[i].z + vals[i].w;
    }
    red[t] = l;
    __syncthreads();
    for (int off = 128; off > 0; off >>= 1) {
        if (t < off) red[t] += red[t + off];
        __syncthreads();
    }
    if (t == 0) linv_s = 1.f / red[0];
    __syncthreads();
    const float linv = linv_s;

#pragma unroll
    for (int i = 0; i < 4; ++i) {
        const float4 v = vals[i];
        wo4[i * 256 + t] =
            make_float4(v.x * linv, v.y * linv, v.z * linv, v.w * linv);
    }

    float a = 0.f;
#pragma unroll 8
    for (int c = 0; c < 64; ++c)
        a += part[((size_t)(b * 64 + c)) * HH + t];
    ctx_out[b * HH + t] = a * linv;
}

// ---------------------------------------------------------------------------
extern "C" void kernel_launch(void* const* d_in, const int* in_sizes, int n_in,
                              void* d_out, int out_size, void* d_ws, size_t ws_size,
                              hipStream_t stream) {
    const float* hidden = (const float*)d_in[0];
    const float* enc    = (const float*)d_in[1];
    const float* W1_w   = (const float*)d_in[2];
    const float* W1_b   = (const float*)d_in[3];
    const float* W2_w   = (const float*)d_in[4];
    const float* W2_b   = (const float*)d_in[5];
    const float* V_w    = (const float*)d_in[6];
    const float* V_b    = (const float*)d_in[7];
    (void)V_b;  // cancels in the shifted softmax

    float* out_weights = (float*)d_out;                 // B*S
    float* out_ctx     = (float*)d_out + BB * SS;       // B*H

    float* ws      = (float*)d_ws;
    float* ws_qq   = ws;                                 // 8192
    float* ws_part = ws_qq + BB * HH;                    // 524288
    float* ws_M    = ws_part + BB * 64 * HH;             // 1
    ushort* ws_w2  = (ushort*)(ws_M + 4);                // 65536 bf16

    prep_kernel<<<dim3(256 + BB + 1), dim3(256), 0, stream>>>(
        W2_w, ws_w2, hidden, W1_w, W1_b, W2_b, V_w, ws_qq, ws_M);
    score_ctx_kernel<<<dim3(SS / 64, BB), dim3(256), 0, stream>>>(
        enc, ws_w2, ws_qq, V_w, ws_M, out_weights, ws_part);
    finish_kernel<<<dim3(BB), dim3(256), 0, stream>>>(
        ws_part, out_weights, out_ctx);
}